// Round 8
// baseline (70.731 us; speedup 1.0000x reference)
//
#include <hip/hip_runtime.h>
#include <hip/hip_bf16.h>
#include <hip/hip_fp16.h>

// MiniBatchDiscrimination: out = concat([x, sum_b2 exp(-L1(act_b, act_b2))], axis=1)
// B=512, F=512, K=50, D=16.  act = x @ W : (512, 800).
// Round 8: SINGLE dispatch, work-stealing fusion.
//  - 40 producer GEMM tiles (64 rows x 160 cols) drawn from a monotonic u64 ticket
//    pool by whichever blocks are resident (no waits in producer phase -> no deadlock).
//  - Epoch derived from each block's exit ticket (pool stride 840 = 40 + 800);
//    per-call invariants hold by pigeonhole, no state reset needed (graph/rocprof safe).
//  - act stored f16; publish via fence(release,system)+system atomicAdd(done[nc]),
//    consume via bounded spin + fence(acquire,system).
//  - Consumers: static (k, chunk) = (bid>>4, bid&15), R7's proven f16 pairwise.

#define B_ROWS 512
#define F_IN   512
#define NK     50
#define DK     16
#define N_COLS (NK * DK)      // 800
#define OUT_COLS (F_IN + NK)  // 562
#define NBLOCKS 800
#define NPROD   40            // 8 m-chunks x 5 n-chunks
#define POOL    (NPROD + NBLOCKS)   // 840

#if __has_builtin(__builtin_amdgcn_exp2f)
#define EXP2F __builtin_amdgcn_exp2f
#else
#define EXP2F exp2f
#endif

typedef __attribute__((ext_vector_type(8))) short bf16x8;
typedef __attribute__((ext_vector_type(4))) float f32x4;

__device__ unsigned long long g_ticket = 0;                 // monotonic across calls
__device__ unsigned long long g_done[5] = {0, 0, 0, 0, 0};  // +8 per n-chunk per call

__device__ __forceinline__ short bfs(float f) {
    __hip_bfloat16 h = __float2bfloat16(f);   // RNE; pairs fuse to v_cvt_pk_bf16_f32
    return *reinterpret_cast<short*>(&h);
}

__global__ __launch_bounds__(256) void fused_kernel(const float* __restrict__ x,
                                                    const float* __restrict__ W,
                                                    __half* __restrict__ act_h,
                                                    float* __restrict__ out) {
    __shared__ uint2 Ah4[2048];              // 16 KB pairwise stage (swizzled half4 slots)
    __shared__ unsigned long long sTk;

    const int bid = blockIdx.x;              // 0..799
    const int tid = threadIdx.x;             // 0..255
    const int wave = tid >> 6, l = tid & 63;
    const int rc = l & 15, kg = l >> 4;

    // ================= producer phase: drain the 40-tile pool =================
    unsigned long long epoch;
    for (;;) {
        __syncthreads();                     // protect sTk from prev-iter readers
        if (tid == 0) sTk = atomicAdd(&g_ticket, 1ULL);
        __syncthreads();
        const unsigned long long t = sTk;
        const unsigned r = (unsigned)(t % POOL);
        if (r >= NPROD) { epoch = t / POOL; break; }

        // ---- produce tile r: rows [64mc, +64), cols [160nc, +160), K = 512 ----
        const int mc = r / 5, ncp = r % 5;
        const int wm = (wave >> 1) & 1, wn = wave & 1;        // 2m x 2n wave grid
        const int rowb = mc * 64 + wm * 32;                    // + mf*16
        const int colb = ncp * 160 + wn * 80;                  // + nf*16

        const float* paw = x + (rowb + rc) * F_IN + kg * 8;
        const float* pbw = W + (kg * 8) * N_COLS + colb + rc;

        f32x4 acc[2][5] = {};
        #pragma unroll 2
        for (int ks = 0; ks < 16; ++ks) {
            bf16x8 a[2];
            #pragma unroll
            for (int mf = 0; mf < 2; ++mf) {
                float4 a0 = *(const float4*)(paw + mf * 16 * F_IN + ks * 32);
                float4 a1 = *(const float4*)(paw + mf * 16 * F_IN + ks * 32 + 4);
                a[mf][0] = bfs(a0.x); a[mf][1] = bfs(a0.y);
                a[mf][2] = bfs(a0.z); a[mf][3] = bfs(a0.w);
                a[mf][4] = bfs(a1.x); a[mf][5] = bfs(a1.y);
                a[mf][6] = bfs(a1.z); a[mf][7] = bfs(a1.w);
            }
            const float* pk = pbw + ks * 32 * N_COLS;
            #pragma unroll
            for (int nf = 0; nf < 5; ++nf) {
                bf16x8 b;
                #pragma unroll
                for (int j = 0; j < 8; ++j)
                    b[j] = bfs(pk[j * N_COLS + nf * 16]);
                acc[0][nf] = __builtin_amdgcn_mfma_f32_16x16x32_bf16(a[0], b, acc[0][nf], 0, 0, 0);
                acc[1][nf] = __builtin_amdgcn_mfma_f32_16x16x32_bf16(a[1], b, acc[1][nf], 0, 0, 0);
            }
        }
        // store act tile as f16 (RNE).  C/D: col = l&15, row = kg*4 + r4  [m89]
        #pragma unroll
        for (int mf = 0; mf < 2; ++mf)
            #pragma unroll
            for (int nf = 0; nf < 5; ++nf)
                #pragma unroll
                for (int r4 = 0; r4 < 4; ++r4) {
                    int row = rowb + mf * 16 + kg * 4 + r4;
                    int col = colb + nf * 16 + rc;
                    act_h[row * N_COLS + col] = __float2half(acc[mf][nf][r4]);
                }

        // x passthrough copy rides on the 8 nc==0 tiles (rows 64mc..+64)
        if (ncp == 0) {
            #pragma unroll
            for (int i = 0; i < 32; ++i) {
                int idx = tid + i * 256;           // 0..8191 float4
                int rr = idx >> 7, c4 = idx & 127;
                float4 v = *(const float4*)(x + (mc * 64 + rr) * F_IN + c4 * 4);
                float* o = out + (mc * 64 + rr) * OUT_COLS + c4 * 4;  // 8B-aligned
                *(float2*)o = make_float2(v.x, v.y);
                *(float2*)(o + 2) = make_float2(v.z, v.w);
            }
        }

        __syncthreads();                     // all waves' stores at vmcnt(0)
        if (tid == 0) {
            __builtin_amdgcn_fence(__ATOMIC_RELEASE, "");   // system: L2 writeback
            __hip_atomic_fetch_add(&g_done[ncp], 1ULL,
                                   __ATOMIC_RELAXED, __HIP_MEMORY_SCOPE_SYSTEM);
        }
    }

    // ================= consumer phase: static tile (k, chunk) =================
    const int k = bid >> 4;                  // 0..49
    const int chunk = bid & 15;              // 0..15
    const int nc = k / 10;                   // n-chunk holding cols k*16..+16
    const unsigned long long target = 8ULL * (epoch + 1);

    if (tid == 0) {
        for (int it = 0; it < 3000000; ++it) {   // bounded: loud-wrong, never hangs
            if (__hip_atomic_load(&g_done[nc], __ATOMIC_RELAXED,
                                  __HIP_MEMORY_SCOPE_SYSTEM) >= target) break;
        }
    }
    __syncthreads();
    __builtin_amdgcn_fence(__ATOMIC_ACQUIRE, "");  // system: invalidate caches

    // stage act[:, k-slice] (512 x 16 f16 = 16 KB), swizzled: phys = s ^ ((s>>6)&15)
    {
        const __half* base = act_h + k * DK;
        #pragma unroll
        for (int i = 0; i < 8; ++i) {
            int idx = tid + i * 256;         // logical half4 slot 0..2047
            int b = idx >> 2, d4 = idx & 3;
            uint2 u = *(const uint2*)(base + b * N_COLS + d4 * 4);
            Ah4[idx ^ ((idx >> 6) & 15)] = u;
        }
    }
    __syncthreads();

    const int rt = tid >> 5;                 // 0..7 -> 4 rows each
    const int q = tid & 31;                  // 0..31 -> 16 b2 each
    const int row0 = chunk * 32 + rt * 4;

    __half2 m[4][8];
    #pragma unroll
    for (int r = 0; r < 4; ++r) {
        int gr = row0 + r;
        int xr = (gr >> 4) & 15;
        #pragma unroll
        for (int j = 0; j < 4; ++j) {
            uint2 u = Ah4[(gr * 4 + j) ^ xr];
            m[r][2 * j]     = __builtin_bit_cast(__half2, u.x);
            m[r][2 * j + 1] = __builtin_bit_cast(__half2, u.y);
        }
    }

    const uint2* bq = Ah4 + q * 64;          // 16 b2 x 4 slots
    const int xm = q & 15;

    float acc[4] = {0.f, 0.f, 0.f, 0.f};
    #pragma unroll 4
    for (int i = 0; i < 16; ++i) {
        __half2 v[8];
        #pragma unroll
        for (int j = 0; j < 4; ++j) {
            uint2 u = bq[(i * 4 + j) ^ xm];
            v[2 * j]     = __builtin_bit_cast(__half2, u.x);
            v[2 * j + 1] = __builtin_bit_cast(__half2, u.y);
        }
        #pragma unroll
        for (int r = 0; r < 4; ++r) {
            __half2 s = __habs2(__hsub2(m[r][0], v[0]));
            #pragma unroll
            for (int jj = 1; jj < 8; ++jj)
                s = __hadd2(s, __habs2(__hsub2(m[r][jj], v[jj])));
            float2 f = __half22float2(s);
            acc[r] += EXP2F((f.x + f.y) * -1.4426950408889634f);
        }
    }

    #pragma unroll
    for (int r = 0; r < 4; ++r) {
        acc[r] += __shfl_xor(acc[r], 1);
        acc[r] += __shfl_xor(acc[r], 2);
        acc[r] += __shfl_xor(acc[r], 4);
        acc[r] += __shfl_xor(acc[r], 8);
        acc[r] += __shfl_xor(acc[r], 16);
    }
    if (q == 0) {
        #pragma unroll
        for (int r = 0; r < 4; ++r)
            out[(row0 + r) * OUT_COLS + F_IN + k] = acc[r];
    }
}

extern "C" void kernel_launch(void* const* d_in, const int* in_sizes, int n_in,
                              void* d_out, int out_size, void* d_ws, size_t ws_size,
                              hipStream_t stream) {
    const float* x = (const float*)d_in[0];   // (512, 512) fp32
    const float* W = (const float*)d_in[1];   // (512, 800) fp32
    float* out = (float*)d_out;               // (512, 562) fp32
    __half* act_h = (__half*)d_ws;            // (512, 800) f16 scratch (800 KB)

    fused_kernel<<<dim3(NBLOCKS), dim3(256), 0, stream>>>(x, W, act_h, out);
}

// Round 9
// 48.960 us; speedup vs baseline: 1.4447x; 1.4447x over previous
//
#include <hip/hip_runtime.h>
#include <hip/hip_bf16.h>
#include <hip/hip_fp16.h>

// MiniBatchDiscrimination: out = concat([x, sum_b2 exp(-L1(act_b, act_b2))], axis=1)
// B=512, F=512, K=50, D=16.  act = x @ W : (512, 800).
// Round 9: R7 structure + SYMMETRIC pairwise (l1[b,b2]=l1[b2,b]): only chunk-pairs
// ci<=cj computed (53% of pair work), results scattered via atomicAdd.
// GEMM dispatch zero-inits the feature region (runs strictly before pairwise).

#define B_ROWS 512
#define F_IN   512
#define NK     50
#define DK     16
#define N_COLS (NK * DK)      // 800
#define OUT_COLS (F_IN + NK)  // 562

#if __has_builtin(__builtin_amdgcn_exp2f)
#define EXP2F __builtin_amdgcn_exp2f
#else
#define EXP2F exp2f
#endif

typedef __attribute__((ext_vector_type(8))) short bf16x8;
typedef __attribute__((ext_vector_type(4))) float f32x4;

__device__ __forceinline__ short bfs(float f) {
    __hip_bfloat16 h = __float2bfloat16(f);   // RNE; pairs fuse to v_cvt_pk_bf16_f32
    return *reinterpret_cast<short*>(&h);
}

// ---------------- GEMM: act[512][800] = bf16(x) @ bf16(W), K split over 4 waves ----------------
// Grid (32, 25), 256 threads. Block (bx, by) -> rows bx*16..+15, cols by*32..+31.
// Wave w handles K in [w*128, +128): 4 MFMA steps; cross-wave LDS reduce.
// Blocks flat-id < 128 copy x into out[:, 0:512]; flat-id < 50 zero out[:, 512+bid].
__global__ __launch_bounds__(256) void gemm_ksplit_kernel(const float* __restrict__ x,
                                                          const float* __restrict__ W,
                                                          float* __restrict__ act,
                                                          float* __restrict__ out) {
    __shared__ float red[4 * 64 * 8];   // 8 KB: [wave][lane][8]

    const int tid = threadIdx.x;
    const int wave = tid >> 6, l = tid & 63;
    const int bid = blockIdx.y * 32 + blockIdx.x;   // 0..799

    // x passthrough copy on 128 blocks (2 float4 per thread)
    if (bid < 128) {
        #pragma unroll
        for (int i = 0; i < 2; ++i) {
            int gid = bid * 512 + i * 256 + tid;    // 0..65535
            int row = gid >> 7, c4 = gid & 127;
            float4 v = ((const float4*)x)[gid];
            float* o = out + row * OUT_COLS + c4 * 4;   // 8B-aligned (562 even)
            *(float2*)o = make_float2(v.x, v.y);
            *(float2*)(o + 2) = make_float2(v.z, v.w);
        }
    }
    // feature region zero-init: block b (<50) zeroes out[:, 512+b]
    if (bid < 50) {
        out[tid * OUT_COLS + F_IN + bid] = 0.f;
        out[(tid + 256) * OUT_COLS + F_IN + bid] = 0.f;
    }

    const int mBase = blockIdx.x * 16;
    const int nBase = blockIdx.y * 32;
    const int rc = l & 15, kg = l >> 4;

    const float* pa = x + (mBase + rc) * F_IN + wave * 128 + kg * 8;
    const float* pb = W + (wave * 128 + kg * 8) * N_COLS + nBase + rc;

    f32x4 acc0 = {0.f, 0.f, 0.f, 0.f};
    f32x4 acc1 = {0.f, 0.f, 0.f, 0.f};

    #pragma unroll
    for (int ks = 0; ks < 4; ++ks) {
        float4 a0 = *(const float4*)(pa + ks * 32);
        float4 a1 = *(const float4*)(pa + ks * 32 + 4);
        bf16x8 a;
        a[0] = bfs(a0.x); a[1] = bfs(a0.y); a[2] = bfs(a0.z); a[3] = bfs(a0.w);
        a[4] = bfs(a1.x); a[5] = bfs(a1.y); a[6] = bfs(a1.z); a[7] = bfs(a1.w);

        const float* pk = pb + (ks * 32) * N_COLS;
        bf16x8 b0, b1;
        #pragma unroll
        for (int j = 0; j < 8; ++j) {
            b0[j] = bfs(pk[j * N_COLS]);
            b1[j] = bfs(pk[j * N_COLS + 16]);
        }
        acc0 = __builtin_amdgcn_mfma_f32_16x16x32_bf16(a, b0, acc0, 0, 0, 0);
        acc1 = __builtin_amdgcn_mfma_f32_16x16x32_bf16(a, b1, acc1, 0, 0, 0);
    }

    // cross-wave reduce: red[wave][lane][0..3]=acc0, [4..7]=acc1
    const int ro = (wave * 64 + l) * 8;
    *(f32x4*)(red + ro)     = acc0;
    *(f32x4*)(red + ro + 4) = acc1;
    __syncthreads();

    // thread sums one float2 (elements e, e+1) over 4 waves.
    // e = 2*tid: le = e>>3 (lane), j0 = e&7; j<4 -> acc0[j] (fr=0), j>=4 -> acc1 (fr=1).
    {
        const int e = tid * 2;
        const int le = e >> 3, j0 = e & 7;
        float2 s = make_float2(0.f, 0.f);
        #pragma unroll
        for (int w = 0; w < 4; ++w) {
            float2 v = *(const float2*)(red + w * 512 + e);
            s.x += v.x; s.y += v.y;
        }
        const int row = mBase + (le >> 4) * 4 + (j0 & 3);
        const int col = nBase + (le & 15) + (j0 >> 2) * 16;
        act[row * N_COLS + col]       = s.x;
        act[(row + 1) * N_COLS + col] = s.y;
    }
}

// ---------------- Symmetric pairwise: block = (pair-tile p, kernel k) ----------------
// p -> (ci, cj), ci <= cj over 16 chunks of 32 rows. 256 thr = 8 rt x 32 q.
// Thread (rt, q): 4 pairs (i = ci*32 + rt*4 + r, j = cj*32 + q), f16 packed math.
// i-side: shfl-reduce over q lanes -> 32 atomicAdds. j-side (ci != cj only):
// shfl_xor(32) + LDS cross-wave reduce -> 32 atomicAdds.
__global__ __launch_bounds__(256) void pairwise_sym_kernel(const float* __restrict__ act,
                                                           float* __restrict__ out) {
    __shared__ uint2 St[256];     // 64 rows x 4 half4 slots (2 KB)
    __shared__ float Jr[4][32];   // j-side cross-wave reduce

    const int p = blockIdx.x;     // 0..135
    const int k = blockIdx.y;     // 0..49
    const int tid = threadIdx.x;

    // p -> (ci, cj), ci<=cj (row-major upper triangle)
    int ci = 0, pp = p;
    while (pp >= 16 - ci) { pp -= 16 - ci; ++ci; }
    const int cj = ci + pp;
    const bool diag = (ci == cj);

    // stage 64 rows (32 of ci, 32 of cj) x 16 f32 -> f16; 1 float4 per thread
    {
        const int rl = tid >> 2, d4 = tid & 3;            // row-local 0..63, slot 0..3
        const int grow = (rl < 32 ? ci * 32 + rl : cj * 32 + rl - 32);
        float4 v = *(const float4*)(act + grow * N_COLS + k * DK + d4 * 4);
        __half2 h0 = __float22half2_rn(make_float2(v.x, v.y));
        __half2 h1 = __float22half2_rn(make_float2(v.z, v.w));
        uint2 u;
        u.x = __builtin_bit_cast(unsigned, h0);
        u.y = __builtin_bit_cast(unsigned, h1);
        St[rl * 4 + d4] = u;
    }
    __syncthreads();

    const int rt = tid >> 5;      // 0..7
    const int q = tid & 31;       // 0..31 -> j row within cj

    // m rows (4) from ci half of St; v row (1) from cj half
    __half2 m[4][8], v[8];
    #pragma unroll
    for (int r = 0; r < 4; ++r)
        #pragma unroll
        for (int j = 0; j < 4; ++j) {
            uint2 u = St[(rt * 4 + r) * 4 + j];           // broadcast across q
            m[r][2 * j]     = __builtin_bit_cast(__half2, u.x);
            m[r][2 * j + 1] = __builtin_bit_cast(__half2, u.y);
        }
    #pragma unroll
    for (int j = 0; j < 4; ++j) {
        uint2 u = St[(32 + q) * 4 + j];
        v[2 * j]     = __builtin_bit_cast(__half2, u.x);
        v[2 * j + 1] = __builtin_bit_cast(__half2, u.y);
    }

    float e[4];
    #pragma unroll
    for (int r = 0; r < 4; ++r) {
        __half2 s = __habs2(__hsub2(m[r][0], v[0]));
        #pragma unroll
        for (int jj = 1; jj < 8; ++jj)
            s = __hadd2(s, __habs2(__hsub2(m[r][jj], v[jj])));
        float2 f = __half22float2(s);
        e[r] = EXP2F((f.x + f.y) * -1.4426950408889634f);
    }

    // ---- i-side: sum over q (32 j-partners) ----
    float ai[4] = {e[0], e[1], e[2], e[3]};
    #pragma unroll
    for (int r = 0; r < 4; ++r) {
        ai[r] += __shfl_xor(ai[r], 1);
        ai[r] += __shfl_xor(ai[r], 2);
        ai[r] += __shfl_xor(ai[r], 4);
        ai[r] += __shfl_xor(ai[r], 8);
        ai[r] += __shfl_xor(ai[r], 16);
    }
    if (q == 0) {
        #pragma unroll
        for (int r = 0; r < 4; ++r)
            atomicAdd(&out[(ci * 32 + rt * 4 + r) * OUT_COLS + F_IN + k], ai[r]);
    }

    // ---- j-side mirror (off-diagonal only): sum over the 32 i-rows ----
    if (!diag) {
        float aj = (e[0] + e[1]) + (e[2] + e[3]);
        aj += __shfl_xor(aj, 32);             // combine rt pairs within wave
        const int wv = tid >> 6, l = tid & 63;
        if (l < 32) Jr[wv][l] = aj;
        __syncthreads();
        if (tid < 32) {
            float s = (Jr[0][tid] + Jr[1][tid]) + (Jr[2][tid] + Jr[3][tid]);
            atomicAdd(&out[(cj * 32 + tid) * OUT_COLS + F_IN + k], s);
        }
    }
}

extern "C" void kernel_launch(void* const* d_in, const int* in_sizes, int n_in,
                              void* d_out, int out_size, void* d_ws, size_t ws_size,
                              hipStream_t stream) {
    const float* x = (const float*)d_in[0];   // (512, 512) fp32
    const float* W = (const float*)d_in[1];   // (512, 800) fp32
    float* out = (float*)d_out;               // (512, 562) fp32
    float* act = (float*)d_ws;                // (512, 800) fp32 scratch

    gemm_ksplit_kernel<<<dim3(32, 25), dim3(256), 0, stream>>>(x, W, act, out);
    pairwise_sym_kernel<<<dim3(136, 50), dim3(256), 0, stream>>>(act, out);
}

// Round 10
// 30.416 us; speedup vs baseline: 2.3255x; 1.6097x over previous
//
#include <hip/hip_runtime.h>
#include <hip/hip_bf16.h>
#include <hip/hip_fp16.h>

// MiniBatchDiscrimination: out = concat([x, sum_b2 exp(-L1(act_b, act_b2))], axis=1)
// B=512, F=512, K=50, D=16.  act = x @ W : (512, 800).
// Round 10: R7 structure (proven 32.0 us) + act stored as f16 by the GEMM
// (bit-identical to R7's stage-time conversion; halves act traffic, removes
// consumer-side cvt). Two dispatches; fusion abandoned after 3 attempts.

#define B_ROWS 512
#define F_IN   512
#define NK     50
#define DK     16
#define N_COLS (NK * DK)      // 800
#define OUT_COLS (F_IN + NK)  // 562

#if __has_builtin(__builtin_amdgcn_exp2f)
#define EXP2F __builtin_amdgcn_exp2f
#else
#define EXP2F exp2f
#endif

typedef __attribute__((ext_vector_type(8))) short bf16x8;
typedef __attribute__((ext_vector_type(4))) float f32x4;

__device__ __forceinline__ short bfs(float f) {
    __hip_bfloat16 h = __float2bfloat16(f);   // RNE; pairs fuse to v_cvt_pk_bf16_f32
    return *reinterpret_cast<short*>(&h);
}

// ---------------- GEMM: act_h[512][800] = f16( bf16(x) @ bf16(W) ), K split over 4 waves ----
// Grid (32, 25), 256 threads. Block (bx, by) -> rows bx*16..+15, cols by*32..+31.
// Wave w handles K in [w*128, +128): 4 MFMA steps; cross-wave LDS reduce.
// A frag: lane l holds x[mBase + (l&15)][kOff + 8*(l>>4) + j]
// B frag: lane l holds W[kOff + 8*(l>>4) + j][nBase + fr*16 + (l&15)]
// C/D:    col = l&15, row = (l>>4)*4 + reg   [m89 verified]
// Blocks with flat id < 128 also copy x rows into out[:, 0:512].
__global__ __launch_bounds__(256) void gemm_ksplit_kernel(const float* __restrict__ x,
                                                          const float* __restrict__ W,
                                                          __half* __restrict__ act_h,
                                                          float* __restrict__ out) {
    __shared__ float red[4 * 64 * 8];   // 8 KB: [wave][lane][8]

    const int tid = threadIdx.x;
    const int wave = tid >> 6, l = tid & 63;
    const int bid = blockIdx.y * 32 + blockIdx.x;   // 0..799

    // x passthrough copy on 128 blocks (2 float4 per thread)
    if (bid < 128) {
        #pragma unroll
        for (int i = 0; i < 2; ++i) {
            int gid = bid * 512 + i * 256 + tid;    // 0..65535
            int row = gid >> 7, c4 = gid & 127;
            float4 v = ((const float4*)x)[gid];
            float* o = out + row * OUT_COLS + c4 * 4;   // 8B-aligned (562 even)
            *(float2*)o = make_float2(v.x, v.y);
            *(float2*)(o + 2) = make_float2(v.z, v.w);
        }
    }

    const int mBase = blockIdx.x * 16;
    const int nBase = blockIdx.y * 32;
    const int rc = l & 15, kg = l >> 4;

    const float* pa = x + (mBase + rc) * F_IN + wave * 128 + kg * 8;
    const float* pb = W + (wave * 128 + kg * 8) * N_COLS + nBase + rc;

    f32x4 acc0 = {0.f, 0.f, 0.f, 0.f};
    f32x4 acc1 = {0.f, 0.f, 0.f, 0.f};

    #pragma unroll
    for (int ks = 0; ks < 4; ++ks) {
        float4 a0 = *(const float4*)(pa + ks * 32);
        float4 a1 = *(const float4*)(pa + ks * 32 + 4);
        bf16x8 a;
        a[0] = bfs(a0.x); a[1] = bfs(a0.y); a[2] = bfs(a0.z); a[3] = bfs(a0.w);
        a[4] = bfs(a1.x); a[5] = bfs(a1.y); a[6] = bfs(a1.z); a[7] = bfs(a1.w);

        const float* pk = pb + (ks * 32) * N_COLS;
        bf16x8 b0, b1;
        #pragma unroll
        for (int j = 0; j < 8; ++j) {
            b0[j] = bfs(pk[j * N_COLS]);
            b1[j] = bfs(pk[j * N_COLS + 16]);
        }
        acc0 = __builtin_amdgcn_mfma_f32_16x16x32_bf16(a, b0, acc0, 0, 0, 0);
        acc1 = __builtin_amdgcn_mfma_f32_16x16x32_bf16(a, b1, acc1, 0, 0, 0);
    }

    // cross-wave reduce: red[wave][lane][0..3]=acc0, [4..7]=acc1
    const int ro = (wave * 64 + l) * 8;
    *(f32x4*)(red + ro)     = acc0;
    *(f32x4*)(red + ro + 4) = acc1;
    __syncthreads();

    // thread sums one float2 (elements e, e+1) over the 4 waves, stores f16.
    // e = 2*tid: le = e>>3 (lane), j0 = e&7; j<4 -> acc0[j] (fr=0), j>=4 -> acc1 (fr=1).
    // elements e, e+1 are rows (j0&3), (j0&3)+1 at the same column.
    {
        const int e = tid * 2;
        const int le = e >> 3, j0 = e & 7;
        float2 s = make_float2(0.f, 0.f);
        #pragma unroll
        for (int w = 0; w < 4; ++w) {
            float2 v = *(const float2*)(red + w * 512 + e);
            s.x += v.x; s.y += v.y;
        }
        const int row = mBase + (le >> 4) * 4 + (j0 & 3);
        const int col = nBase + (le & 15) + (j0 >> 2) * 16;
        act_h[row * N_COLS + col]       = __float2half(s.x);   // RNE, same as R7 staging
        act_h[(row + 1) * N_COLS + col] = __float2half(s.y);
    }
}

// ---------------- Pairwise L1 + exp-sum, packed f16, 4 rows/thread ----------------
// Grid (50, 16): block = (kernel k, 32-row chunk). 256 threads = 8 row-threads x 32 q.
// LDS: row b as 4 half4 (uint2) slots; logical slot s = b*4 + j stored at s ^ ((s>>6)&15)
// so q-group reads (stride 64 slots = 512B) spread across all 16 bank-pairs.
__global__ __launch_bounds__(256) void pairwise_h2_kernel(const __half* __restrict__ act_h,
                                                          float* __restrict__ out) {
    const int k = blockIdx.x;          // 0..49
    const int chunk = blockIdx.y;      // 0..15
    __shared__ uint2 Ah4[B_ROWS * 4];  // 16 KB, swizzled half4 slots

    const int tid = threadIdx.x;
    const __half* base = act_h + k * DK;
    #pragma unroll
    for (int i = 0; i < 8; ++i) {
        int idx = tid + i * 256;       // logical half4 slot 0..2047
        int b = idx >> 2, d4 = idx & 3;
        uint2 u = *(const uint2*)(base + b * N_COLS + d4 * 4);   // 8B-aligned
        Ah4[idx ^ ((idx >> 6) & 15)] = u;
    }
    __syncthreads();

    const int rt = tid >> 5;           // 0..7 -> 4 rows each
    const int q = tid & 31;            // 0..31 -> 16 b2 each
    const int row0 = chunk * 32 + rt * 4;

    // 4 m-rows in registers: 8 half2 per row
    __half2 m[4][8];
    #pragma unroll
    for (int r = 0; r < 4; ++r) {
        int gr = row0 + r;
        int xr = (gr >> 4) & 15;
        #pragma unroll
        for (int j = 0; j < 4; ++j) {
            uint2 u = Ah4[(gr * 4 + j) ^ xr];
            m[r][2 * j]     = __builtin_bit_cast(__half2, u.x);
            m[r][2 * j + 1] = __builtin_bit_cast(__half2, u.y);
        }
    }

    const uint2* bq = Ah4 + q * 64;    // 16 b2 x 4 slots
    const int xm = q & 15;

    float acc[4] = {0.f, 0.f, 0.f, 0.f};
    #pragma unroll 4
    for (int i = 0; i < 16; ++i) {
        __half2 v[8];
        #pragma unroll
        for (int j = 0; j < 4; ++j) {
            uint2 u = bq[(i * 4 + j) ^ xm];
            v[2 * j]     = __builtin_bit_cast(__half2, u.x);
            v[2 * j + 1] = __builtin_bit_cast(__half2, u.y);
        }
        #pragma unroll
        for (int r = 0; r < 4; ++r) {
            __half2 s = __habs2(__hsub2(m[r][0], v[0]));
            #pragma unroll
            for (int jj = 1; jj < 8; ++jj)
                s = __hadd2(s, __habs2(__hsub2(m[r][jj], v[jj])));
            float2 f = __half22float2(s);
            acc[r] += EXP2F((f.x + f.y) * -1.4426950408889634f);
        }
    }

    #pragma unroll
    for (int r = 0; r < 4; ++r) {
        acc[r] += __shfl_xor(acc[r], 1);
        acc[r] += __shfl_xor(acc[r], 2);
        acc[r] += __shfl_xor(acc[r], 4);
        acc[r] += __shfl_xor(acc[r], 8);
        acc[r] += __shfl_xor(acc[r], 16);
    }
    if (q == 0) {
        #pragma unroll
        for (int r = 0; r < 4; ++r)
            out[(row0 + r) * OUT_COLS + F_IN + k] = acc[r];
    }
}

extern "C" void kernel_launch(void* const* d_in, const int* in_sizes, int n_in,
                              void* d_out, int out_size, void* d_ws, size_t ws_size,
                              hipStream_t stream) {
    const float* x = (const float*)d_in[0];   // (512, 512) fp32
    const float* W = (const float*)d_in[1];   // (512, 800) fp32
    float* out = (float*)d_out;               // (512, 562) fp32
    __half* act_h = (__half*)d_ws;            // (512, 800) f16 scratch (800 KB)

    gemm_ksplit_kernel<<<dim3(32, 25), dim3(256), 0, stream>>>(x, W, act_h, out);
    pairwise_h2_kernel<<<dim3(50, 16), dim3(256), 0, stream>>>(act_h, out);
}